// Round 12
// baseline (204.307 us; speedup 1.0000x reference)
//
#include <hip/hip_runtime.h>

#define N_NODES 100000
#define BSH 9                           // 512 nodes per bucket
#define NBKT ((N_NODES + 511) >> BSH)   // 196
#define CH 7168                         // items per partition chunk
#define SLACK 10240                     // per-bucket slack allocation

typedef unsigned int u32;
typedef unsigned short u16;
typedef unsigned char u8;
typedef __attribute__((ext_vector_type(8))) short s8v;   // 8 bf16 (4 VGPRs)
typedef __attribute__((ext_vector_type(4))) float f4v;   // 4 f32 acc

static __device__ __forceinline__ u16 f2bf(float f) {  // round-nearest-even
    union { float f; u32 u; } c; c.f = f;
    u32 r = (c.u + 0x7fffu + ((c.u >> 16) & 1u)) >> 16;
    return (u16)r;
}
static __device__ __forceinline__ float bf2f_u(u16 h) {
    union { u32 u; float f; } c; c.u = ((u32)h) << 16;
    return c.f;
}
static __device__ __forceinline__ void acc2(u32 p, float& a, float& b) {
    union { u32 u; float f; } lo, hi;
    lo.u = p << 16;
    hi.u = p & 0xffff0000u;
    a += lo.f;
    b += hi.f;
}
static __device__ __forceinline__ void acc8(uint4 p, float* a) {
    acc2(p.x, a[0], a[1]); acc2(p.y, a[2], a[3]);
    acc2(p.z, a[4], a[5]); acc2(p.w, a[6], a[7]);
}

// ============ CSR build (slack buckets, packed items) ============
// item e in [0,E) = edge (src[e],dst[e]); e in [E,E+N) = self-loop (v,v).
// packed item = ((dst & 511) << 17) | src    (src < 2^17)

__global__ __launch_bounds__(256) void initcur_k(int* __restrict__ bcur) {
    bcur[threadIdx.x] = threadIdx.x * SLACK;
}

__global__ __launch_bounds__(256) void partition_k(const int* __restrict__ src,
        const int* __restrict__ dst, int* __restrict__ bcur,
        u32* __restrict__ bktBuf, int E, int TOT) {
    __shared__ int hist[256];
    __shared__ int lbase[256];
    __shared__ int gbase[256];
    __shared__ int ps[256];
    __shared__ u32 stage[CH];
    __shared__ u8 stageB[CH];
    int t = threadIdx.x;
    int base = blockIdx.x * CH;
    int cnt = min(CH, TOT - base);
    hist[t] = 0;
    __syncthreads();
    for (int i = t; i < cnt; i += 256) {
        int e = base + i;
        int d = (e < E) ? dst[e] : e - E;
        atomicAdd(&hist[d >> BSH], 1);
    }
    __syncthreads();
    ps[t] = hist[t];
    __syncthreads();
    for (int off = 1; off < 256; off <<= 1) {
        int val = ps[t];
        int add = (t >= off) ? ps[t - off] : 0;
        __syncthreads();
        ps[t] = val + add;
        __syncthreads();
    }
    lbase[t] = ps[t] - hist[t];
    gbase[t] = atomicAdd(&bcur[t], hist[t]);
    hist[t] = 0;
    __syncthreads();
    for (int i = t; i < cnt; i += 256) {
        int e = base + i;
        int s, d;
        if (e < E) { s = src[e]; d = dst[e]; }
        else       { s = d = e - E; }
        int b = d >> BSH;
        int lpos = lbase[b] + atomicAdd(&hist[b], 1);
        stage[lpos] = ((u32)(d & 511) << 17) | (u32)s;
        stageB[lpos] = (u8)b;
    }
    __syncthreads();
    for (int i = t; i < cnt; i += 256) {
        int b = stageB[i];
        bktBuf[gbase[b] + (i - lbase[b])] = stage[i];
    }
}

__global__ __launch_bounds__(256) void buildfill_k(const int* __restrict__ bcur,
        const u32* __restrict__ bktBuf, int* __restrict__ offsets,
        int* __restrict__ ends, float* __restrict__ dinv,
        int* __restrict__ srt_src) {
    __shared__ int hist[512];
    __shared__ int hscan[512];
    __shared__ int cur[512];
    __shared__ int ps[256];
    int t = threadIdx.x;
    int b = blockIdx.x;
    int v0 = b << BSH;
    int nv = min(512, N_NODES - v0);
    int base = b * SLACK;
    int cnt = bcur[b] - base;
    hist[t] = 0; hist[t + 256] = 0;
    cur[t] = 0;  cur[t + 256] = 0;
    __syncthreads();
    for (int i = t; i < cnt; i += 256)
        atomicAdd(&hist[bktBuf[base + i] >> 17], 1);
    __syncthreads();
    int a = hist[2 * t], bb = hist[2 * t + 1];
    int own = a + bb;
    ps[t] = own;
    __syncthreads();
    for (int off = 1; off < 256; off <<= 1) {
        int val = ps[t];
        int add = (t >= off) ? ps[t - off] : 0;
        __syncthreads();
        ps[t] = val + add;
        __syncthreads();
    }
    int excl2 = ps[t] - own;
    hscan[2 * t] = excl2;
    hscan[2 * t + 1] = excl2 + a;
    __syncthreads();
    for (int j = t; j < nv; j += 256) {
        int o = base + hscan[j];
        offsets[v0 + j] = o;
        ends[v0 + j] = o + hist[j];
        dinv[v0 + j] = rsqrtf((float)hist[j]);
    }
    for (int i = t; i < cnt; i += 256) {
        u32 it = bktBuf[base + i];
        int j = it >> 17;
        int pos = atomicAdd(&cur[j], 1);
        srt_src[base + hscan[j] + pos] = (int)(it & 0x1ffffu);
    }
}

// ============ GEMM1 (MFMA): h1b[N,64](bf16) = dinv[row] * (x[N,128] @ W1) ====

static __device__ __forceinline__ void split8(const float* __restrict__ xp,
                                              s8v& hi, s8v& lo) {
    float4 v0 = *(const float4*)xp;
    float4 v1 = *(const float4*)(xp + 4);
    float xv[8] = {v0.x, v0.y, v0.z, v0.w, v1.x, v1.y, v1.z, v1.w};
#pragma unroll
    for (int j = 0; j < 8; ++j) {
        u16 h = f2bf(xv[j]);
        hi[j] = (short)h;
        lo[j] = (short)f2bf(xv[j] - bf2f_u(h));
    }
}

__global__ __launch_bounds__(256) void gemm1_k(const float* __restrict__ x,
                                               const float* __restrict__ W1,
                                               const float* __restrict__ dinv,
                                               u16* __restrict__ h1b) {
    __shared__ __attribute__((aligned(16))) short Bs[2][4][4][512];
    int t = threadIdx.x;
    for (int i = t; i < 128 * 64; i += 256) {
        int k = i >> 6, c = i & 63;
        float w = W1[i];
        u16 h = f2bf(w);
        u16 l = f2bf(w - bf2f_u(h));
        int ks = k >> 5, kg = (k >> 3) & 3, kk = k & 7;
        int ct = c >> 4, col = c & 15;
        int idx = (kg * 16 + col) * 8 + kk;
        Bs[0][ks][ct][idx] = (short)h;
        Bs[1][ks][ct][idx] = (short)l;
    }
    __syncthreads();

    int lane = t & 63;
    int rows0 = (blockIdx.x * 4 + (t >> 6)) * 32;
    if (rows0 >= N_NODES) return;

    f4v acc[2][4];
#pragma unroll
    for (int rt = 0; rt < 2; ++rt)
#pragma unroll
        for (int ct = 0; ct < 4; ++ct)
            acc[rt][ct] = (f4v){0.f, 0.f, 0.f, 0.f};

    int arow = lane & 15;
    int kgl = lane >> 4;
#pragma unroll
    for (int ks = 0; ks < 4; ++ks) {
        s8v bh[4], bl[4];
#pragma unroll
        for (int ct = 0; ct < 4; ++ct) {
            bh[ct] = *(const s8v*)&Bs[0][ks][ct][lane * 8];
            bl[ct] = *(const s8v*)&Bs[1][ks][ct][lane * 8];
        }
#pragma unroll
        for (int rt = 0; rt < 2; ++rt) {
            s8v ah, al;
            const float* xp = x + (size_t)(rows0 + rt * 16 + arow) * 128
                                + ks * 32 + kgl * 8;
            split8(xp, ah, al);
#pragma unroll
            for (int ct = 0; ct < 4; ++ct) {
                acc[rt][ct] = __builtin_amdgcn_mfma_f32_16x16x32_bf16(
                    ah, bh[ct], acc[rt][ct], 0, 0, 0);
                acc[rt][ct] = __builtin_amdgcn_mfma_f32_16x16x32_bf16(
                    ah, bl[ct], acc[rt][ct], 0, 0, 0);
                acc[rt][ct] = __builtin_amdgcn_mfma_f32_16x16x32_bf16(
                    al, bh[ct], acc[rt][ct], 0, 0, 0);
            }
        }
    }

#pragma unroll
    for (int rt = 0; rt < 2; ++rt) {
        int rbase = rows0 + rt * 16 + ((lane >> 4) << 2);
        float dv[4];
#pragma unroll
        for (int r = 0; r < 4; ++r) dv[r] = dinv[rbase + r];
#pragma unroll
        for (int ct = 0; ct < 4; ++ct) {
            int col = ct * 16 + (lane & 15);
#pragma unroll
            for (int r = 0; r < 4; ++r)
                h1b[(size_t)(rbase + r) * 64 + col] = f2bf(acc[rt][ct][r] * dv[r]);
        }
    }
}

// ============ layer2: h2b = dinv * (relu(dinv*agg + b1) @ W2) ============
// 2 nodes/wave, flattened contiguous range [offsets[v0], ends[v1]) with one
// predicated straddle step at the node boundary. uint4 row reads: 8 lanes x
// 16B = 128B row -> 8 edges per gather instruction (2x fewer vmem instrs).

__global__ __launch_bounds__(256) void layer2_k(const int* __restrict__ offsets,
        const int* __restrict__ ends, const int* __restrict__ srt_src,
        const float* __restrict__ dinv, const u16* __restrict__ h1b,
        const float* __restrict__ b1, const float* __restrict__ W2,
        u16* __restrict__ h2b) {
    __shared__ float W2s[64 * 32];
    __shared__ float b1s[64];
    for (int i = threadIdx.x; i < 64 * 32; i += 256) W2s[i] = W2[i];
    if (threadIdx.x < 64) b1s[threadIdx.x] = b1[threadIdx.x];
    __syncthreads();
    int lane = threadIdx.x & 63;
    int f = lane & 7, q = lane >> 3;      // 8 feat-lanes x 8 edge slots
    int v0 = blockIdx.x * 8 + (threadIdx.x >> 6) * 2;   // grid = N/8
    int v1 = v0 + 1;
    int beg = offsets[v0], m = ends[v0], end = ends[v1];  // ends[v0]==offsets[v1]
    const uint4* rows = (const uint4*)h1b;   // row s = rows + s*8
    float a[8] = {0.f,0.f,0.f,0.f,0.f,0.f,0.f,0.f};
    float c[8] = {0.f,0.f,0.f,0.f,0.f,0.f,0.f,0.f};
    int i = beg;
    // node0 full steps (2x unrolled)
    for (; i + 16 <= m; i += 16) {
        int sA = srt_src[i + q], sB = srt_src[i + 8 + q];
        uint4 pA = rows[(size_t)sA * 8 + f];
        uint4 pB = rows[(size_t)sB * 8 + f];
        acc8(pA, a); acc8(pB, a);
    }
    if (i + 8 <= m) {
        int s = srt_src[i + q];
        acc8(rows[(size_t)s * 8 + f], a);
        i += 8;
    }
    // straddle step over the node boundary
    if (i < m) {
        int j = i + q;
        if (j < end) {
            uint4 p = rows[(size_t)srt_src[j] * 8 + f];
            if (j < m) acc8(p, a); else acc8(p, c);
        }
        i += 8;
    }
    // node1 full steps
    for (; i + 16 <= end; i += 16) {
        int sA = srt_src[i + q], sB = srt_src[i + 8 + q];
        uint4 pA = rows[(size_t)sA * 8 + f];
        uint4 pB = rows[(size_t)sB * 8 + f];
        acc8(pA, c); acc8(pB, c);
    }
    if (i + 8 <= end) {
        int s = srt_src[i + q];
        acc8(rows[(size_t)s * 8 + f], c);
        i += 8;
    }
    if (i + q < end) {
        acc8(rows[(size_t)srt_src[i + q] * 8 + f], c);
    }
    // reduce over edge slots (lane bits 3..5)
#pragma unroll
    for (int j = 0; j < 8; ++j) {
        a[j] += __shfl_xor(a[j], 8, 64);
        a[j] += __shfl_xor(a[j], 16, 64);
        a[j] += __shfl_xor(a[j], 32, 64);
        c[j] += __shfl_xor(c[j], 8, 64);
        c[j] += __shfl_xor(c[j], 16, 64);
        c[j] += __shfl_xor(c[j], 32, 64);
    }
    bool lo = (lane < 32);
    float dv = lo ? dinv[v0] : dinv[v1];
    float r[8];
#pragma unroll
    for (int j = 0; j < 8; ++j) {
        float tv = lo ? a[j] : c[j];
        r[j] = fmaxf(fmaf(dv, tv, b1s[8 * f + j]), 0.f);
    }
    int cc = lane & 31;
    float o = 0.f;
#pragma unroll
    for (int g = 0; g < 8; ++g) {
#pragma unroll
        for (int j = 0; j < 8; ++j)
            o = fmaf(__shfl(r[j], g, 8), W2s[(8 * g + j) * 32 + cc], o);
    }
    int vst = lo ? v0 : v1;
    h2b[(size_t)vst * 32 + cc] = f2bf(dv * o);
}

// ============ layer3: out = relu(dinv*agg(h2b) + b2) @ Wfc + bfc ============
// 4 nodes/wave, flattened range with straddle steps; uint4 row reads:
// 4 lanes x 16B = 64B row -> 16 edges per gather instruction.

__global__ __launch_bounds__(256) void layer3_k(const int* __restrict__ offsets,
        const int* __restrict__ ends, const int* __restrict__ srt_src,
        const float* __restrict__ dinv, const u16* __restrict__ h2b,
        const float* __restrict__ b2, const float* __restrict__ Wfc,
        const float* __restrict__ bfc, float* __restrict__ out) {
    int lane = threadIdx.x & 63;
    int f = lane & 3, q = lane >> 2;      // 4 feat-lanes x 16 edge slots
    int vb = blockIdx.x * 16 + (threadIdx.x >> 6) * 4;   // grid = N/16
    int beg = offsets[vb];
    int m1 = ends[vb], m2 = ends[vb + 1], m3 = ends[vb + 2], end = ends[vb + 3];
    const uint4* rows = (const uint4*)h2b;   // row s = rows + s*4
    float A[8] = {0.f,0.f,0.f,0.f,0.f,0.f,0.f,0.f};
    float B[8] = {0.f,0.f,0.f,0.f,0.f,0.f,0.f,0.f};
    float C[8] = {0.f,0.f,0.f,0.f,0.f,0.f,0.f,0.f};
    float D[8] = {0.f,0.f,0.f,0.f,0.f,0.f,0.f,0.f};
    int i = beg;
#define STRADDLE(MK) \
    if (i < MK) { \
        int j = i + q; \
        if (j < end) { \
            uint4 p = rows[(size_t)srt_src[j] * 4 + f]; \
            if (j < m1) acc8(p, A); \
            else if (j < m2) acc8(p, B); \
            else if (j < m3) acc8(p, C); \
            else acc8(p, D); \
        } \
        i += 16; \
    }
    for (; i + 16 <= m1; i += 16) {
        int s = srt_src[i + q];
        acc8(rows[(size_t)s * 4 + f], A);
    }
    STRADDLE(m1)
    for (; i + 16 <= m2; i += 16) {
        int s = srt_src[i + q];
        acc8(rows[(size_t)s * 4 + f], B);
    }
    STRADDLE(m2)
    for (; i + 16 <= m3; i += 16) {
        int s = srt_src[i + q];
        acc8(rows[(size_t)s * 4 + f], C);
    }
    STRADDLE(m3)
    for (; i + 16 <= end; i += 16) {
        int s = srt_src[i + q];
        acc8(rows[(size_t)s * 4 + f], D);
    }
    if (i + q < end) {
        acc8(rows[(size_t)srt_src[i + q] * 4 + f], D);
    }
#undef STRADDLE
    // reduce over edge slots (lane bits 2..5)
#pragma unroll
    for (int j = 0; j < 8; ++j) {
        A[j] += __shfl_xor(A[j], 4, 64);  A[j] += __shfl_xor(A[j], 8, 64);
        A[j] += __shfl_xor(A[j], 16, 64); A[j] += __shfl_xor(A[j], 32, 64);
        B[j] += __shfl_xor(B[j], 4, 64);  B[j] += __shfl_xor(B[j], 8, 64);
        B[j] += __shfl_xor(B[j], 16, 64); B[j] += __shfl_xor(B[j], 32, 64);
        C[j] += __shfl_xor(C[j], 4, 64);  C[j] += __shfl_xor(C[j], 8, 64);
        C[j] += __shfl_xor(C[j], 16, 64); C[j] += __shfl_xor(C[j], 32, 64);
        D[j] += __shfl_xor(D[j], 4, 64);  D[j] += __shfl_xor(D[j], 8, 64);
        D[j] += __shfl_xor(D[j], 16, 64); D[j] += __shfl_xor(D[j], 32, 64);
    }
    float dv0 = dinv[vb], dv1 = dinv[vb + 1], dv2 = dinv[vb + 2], dv3 = dinv[vb + 3];
    float pr0 = 0.f, pr1 = 0.f, pr2 = 0.f, pr3 = 0.f;
#pragma unroll
    for (int j = 0; j < 8; ++j) {
        int k = 8 * f + j;
        float w = Wfc[k], g = b2[k];
        pr0 += fmaxf(fmaf(dv0, A[j], g), 0.f) * w;
        pr1 += fmaxf(fmaf(dv1, B[j], g), 0.f) * w;
        pr2 += fmaxf(fmaf(dv2, C[j], g), 0.f) * w;
        pr3 += fmaxf(fmaf(dv3, D[j], g), 0.f) * w;
    }
    pr0 += __shfl_xor(pr0, 1, 64); pr0 += __shfl_xor(pr0, 2, 64);
    pr1 += __shfl_xor(pr1, 1, 64); pr1 += __shfl_xor(pr1, 2, 64);
    pr2 += __shfl_xor(pr2, 1, 64); pr2 += __shfl_xor(pr2, 2, 64);
    pr3 += __shfl_xor(pr3, 1, 64); pr3 += __shfl_xor(pr3, 2, 64);
    if (lane == 0) {
        float bb = bfc[0];
        out[vb + 0] = pr0 + bb;
        out[vb + 1] = pr1 + bb;
        out[vb + 2] = pr2 + bb;
        out[vb + 3] = pr3 + bb;
    }
}

// ============ launch ============

extern "C" void kernel_launch(void* const* d_in, const int* in_sizes, int n_in,
                              void* d_out, int out_size, void* d_ws, size_t ws_size,
                              hipStream_t stream) {
    const float* x   = (const float*)d_in[0];
    const int*   ei  = (const int*)d_in[1];
    const float* W1  = (const float*)d_in[2];
    const float* b1  = (const float*)d_in[3];
    const float* W2  = (const float*)d_in[4];
    const float* b2  = (const float*)d_in[5];
    const float* Wfc = (const float*)d_in[6];
    const float* bfc = (const float*)d_in[7];
    float* out = (float*)d_out;

    const int E = in_sizes[1] / 2;
    const int TOT = E + N_NODES;
    const int* src = ei;
    const int* dst = ei + E;

    // workspace layout (ints)
    int*   bcur    = (int*)d_ws;                       // 256
    int*   offsets = bcur + 256;                       // N
    int*   ends    = offsets + N_NODES;                // N
    int*   srt_src = ends + N_NODES;                   // NBKT*SLACK (~2.0M)
    u32*   bktBuf  = (u32*)(srt_src + NBKT * SLACK);   // NBKT*SLACK
    float* dinv    = (float*)(bktBuf + NBKT * SLACK);  // N
    u16*   h1b     = (u16*)(dinv + N_NODES);           // 64N bf16
    u16*   h2b     = h1b + (size_t)N_NODES * 64;       // 32N bf16

    const int NCH = (TOT + CH - 1) / CH;

    initcur_k<<<1, 256, 0, stream>>>(bcur);
    partition_k<<<NCH, 256, 0, stream>>>(src, dst, bcur, bktBuf, E, TOT);
    buildfill_k<<<NBKT, 256, 0, stream>>>(bcur, bktBuf, offsets, ends, dinv,
                                          srt_src);

    const int GB1 = (N_NODES / 32 + 3) / 4;   // 782 blocks x 4 waves x 32 rows
    gemm1_k<<<GB1, 256, 0, stream>>>(x, W1, dinv, h1b);

    layer2_k<<<N_NODES / 8, 256, 0, stream>>>(offsets, ends, srt_src, dinv, h1b,
                                              b1, W2, h2b);
    layer3_k<<<N_NODES / 16, 256, 0, stream>>>(offsets, ends, srt_src, dinv, h2b,
                                               b2, Wfc, bfc, out);
}

// Round 13
// 187.468 us; speedup vs baseline: 1.0898x; 1.0898x over previous
//
#include <hip/hip_runtime.h>

#define N_NODES 100000
#define BSH 9                           // 512 nodes per bucket
#define NBKT ((N_NODES + 511) >> BSH)   // 196
#define CH 7168                         // items per partition chunk
#define SLACK 10240                     // per-bucket slack allocation

typedef unsigned int u32;
typedef unsigned short u16;
typedef unsigned char u8;
typedef __attribute__((ext_vector_type(8))) short s8v;   // 8 bf16 (4 VGPRs)
typedef __attribute__((ext_vector_type(4))) float f4v;   // 4 f32 acc

static __device__ __forceinline__ u16 f2bf(float f) {  // round-nearest-even
    union { float f; u32 u; } c; c.f = f;
    u32 r = (c.u + 0x7fffu + ((c.u >> 16) & 1u)) >> 16;
    return (u16)r;
}
static __device__ __forceinline__ float bf2f_u(u16 h) {
    union { u32 u; float f; } c; c.u = ((u32)h) << 16;
    return c.f;
}
static __device__ __forceinline__ void acc2(u32 p, float& a, float& b) {
    union { u32 u; float f; } lo, hi;
    lo.u = p << 16;
    hi.u = p & 0xffff0000u;
    a += lo.f;
    b += hi.f;
}

// ============ CSR build (slack buckets, packed items) ============
// item e in [0,E) = edge (src[e],dst[e]); e in [E,E+N) = self-loop (v,v).
// packed item = ((dst & 511) << 17) | src    (src < 2^17)

__global__ __launch_bounds__(256) void initcur_k(int* __restrict__ bcur) {
    bcur[threadIdx.x] = threadIdx.x * SLACK;
}

__global__ __launch_bounds__(256) void partition_k(const int* __restrict__ src,
        const int* __restrict__ dst, int* __restrict__ bcur,
        u32* __restrict__ bktBuf, int E, int TOT) {
    __shared__ int hist[256];
    __shared__ int lbase[256];
    __shared__ int gbase[256];
    __shared__ int ps[256];
    __shared__ u32 stage[CH];
    __shared__ u8 stageB[CH];
    int t = threadIdx.x;
    int base = blockIdx.x * CH;
    int cnt = min(CH, TOT - base);
    hist[t] = 0;
    __syncthreads();
    for (int i = t; i < cnt; i += 256) {
        int e = base + i;
        int d = (e < E) ? dst[e] : e - E;
        atomicAdd(&hist[d >> BSH], 1);
    }
    __syncthreads();
    ps[t] = hist[t];
    __syncthreads();
    for (int off = 1; off < 256; off <<= 1) {
        int val = ps[t];
        int add = (t >= off) ? ps[t - off] : 0;
        __syncthreads();
        ps[t] = val + add;
        __syncthreads();
    }
    lbase[t] = ps[t] - hist[t];
    gbase[t] = atomicAdd(&bcur[t], hist[t]);
    hist[t] = 0;
    __syncthreads();
    for (int i = t; i < cnt; i += 256) {
        int e = base + i;
        int s, d;
        if (e < E) { s = src[e]; d = dst[e]; }
        else       { s = d = e - E; }
        int b = d >> BSH;
        int lpos = lbase[b] + atomicAdd(&hist[b], 1);
        stage[lpos] = ((u32)(d & 511) << 17) | (u32)s;
        stageB[lpos] = (u8)b;
    }
    __syncthreads();
    for (int i = t; i < cnt; i += 256) {
        int b = stageB[i];
        bktBuf[gbase[b] + (i - lbase[b])] = stage[i];
    }
}

__global__ __launch_bounds__(256) void buildfill_k(const int* __restrict__ bcur,
        const u32* __restrict__ bktBuf, int* __restrict__ offsets,
        int* __restrict__ ends, float* __restrict__ dinv,
        int* __restrict__ srt_src) {
    __shared__ int hist[512];
    __shared__ int hscan[512];
    __shared__ int cur[512];
    __shared__ int ps[256];
    int t = threadIdx.x;
    int b = blockIdx.x;
    int v0 = b << BSH;
    int nv = min(512, N_NODES - v0);
    int base = b * SLACK;
    int cnt = bcur[b] - base;
    hist[t] = 0; hist[t + 256] = 0;
    cur[t] = 0;  cur[t + 256] = 0;
    __syncthreads();
    for (int i = t; i < cnt; i += 256)
        atomicAdd(&hist[bktBuf[base + i] >> 17], 1);
    __syncthreads();
    int a = hist[2 * t], bb = hist[2 * t + 1];
    int own = a + bb;
    ps[t] = own;
    __syncthreads();
    for (int off = 1; off < 256; off <<= 1) {
        int val = ps[t];
        int add = (t >= off) ? ps[t - off] : 0;
        __syncthreads();
        ps[t] = val + add;
        __syncthreads();
    }
    int excl2 = ps[t] - own;
    hscan[2 * t] = excl2;
    hscan[2 * t + 1] = excl2 + a;
    __syncthreads();
    for (int j = t; j < nv; j += 256) {
        int o = base + hscan[j];
        offsets[v0 + j] = o;
        ends[v0 + j] = o + hist[j];
        dinv[v0 + j] = rsqrtf((float)hist[j]);
    }
    for (int i = t; i < cnt; i += 256) {
        u32 it = bktBuf[base + i];
        int j = it >> 17;
        int pos = atomicAdd(&cur[j], 1);
        srt_src[base + hscan[j] + pos] = (int)(it & 0x1ffffu);
    }
}

// ============ GEMM1 (MFMA): h1b[N,64](bf16) = dinv[row] * (x[N,128] @ W1) ====

static __device__ __forceinline__ void split8(const float* __restrict__ xp,
                                              s8v& hi, s8v& lo) {
    float4 v0 = *(const float4*)xp;
    float4 v1 = *(const float4*)(xp + 4);
    float xv[8] = {v0.x, v0.y, v0.z, v0.w, v1.x, v1.y, v1.z, v1.w};
#pragma unroll
    for (int j = 0; j < 8; ++j) {
        u16 h = f2bf(xv[j]);
        hi[j] = (short)h;
        lo[j] = (short)f2bf(xv[j] - bf2f_u(h));
    }
}

__global__ __launch_bounds__(256) void gemm1_k(const float* __restrict__ x,
                                               const float* __restrict__ W1,
                                               const float* __restrict__ dinv,
                                               u16* __restrict__ h1b) {
    __shared__ __attribute__((aligned(16))) short Bs[2][4][4][512];
    int t = threadIdx.x;
    for (int i = t; i < 128 * 64; i += 256) {
        int k = i >> 6, c = i & 63;
        float w = W1[i];
        u16 h = f2bf(w);
        u16 l = f2bf(w - bf2f_u(h));
        int ks = k >> 5, kg = (k >> 3) & 3, kk = k & 7;
        int ct = c >> 4, col = c & 15;
        int idx = (kg * 16 + col) * 8 + kk;
        Bs[0][ks][ct][idx] = (short)h;
        Bs[1][ks][ct][idx] = (short)l;
    }
    __syncthreads();

    int lane = t & 63;
    int rows0 = (blockIdx.x * 4 + (t >> 6)) * 32;
    if (rows0 >= N_NODES) return;

    f4v acc[2][4];
#pragma unroll
    for (int rt = 0; rt < 2; ++rt)
#pragma unroll
        for (int ct = 0; ct < 4; ++ct)
            acc[rt][ct] = (f4v){0.f, 0.f, 0.f, 0.f};

    int arow = lane & 15;
    int kgl = lane >> 4;
#pragma unroll
    for (int ks = 0; ks < 4; ++ks) {
        s8v bh[4], bl[4];
#pragma unroll
        for (int ct = 0; ct < 4; ++ct) {
            bh[ct] = *(const s8v*)&Bs[0][ks][ct][lane * 8];
            bl[ct] = *(const s8v*)&Bs[1][ks][ct][lane * 8];
        }
#pragma unroll
        for (int rt = 0; rt < 2; ++rt) {
            s8v ah, al;
            const float* xp = x + (size_t)(rows0 + rt * 16 + arow) * 128
                                + ks * 32 + kgl * 8;
            split8(xp, ah, al);
#pragma unroll
            for (int ct = 0; ct < 4; ++ct) {
                acc[rt][ct] = __builtin_amdgcn_mfma_f32_16x16x32_bf16(
                    ah, bh[ct], acc[rt][ct], 0, 0, 0);
                acc[rt][ct] = __builtin_amdgcn_mfma_f32_16x16x32_bf16(
                    ah, bl[ct], acc[rt][ct], 0, 0, 0);
                acc[rt][ct] = __builtin_amdgcn_mfma_f32_16x16x32_bf16(
                    al, bh[ct], acc[rt][ct], 0, 0, 0);
            }
        }
    }

#pragma unroll
    for (int rt = 0; rt < 2; ++rt) {
        int rbase = rows0 + rt * 16 + ((lane >> 4) << 2);
        float dv[4];
#pragma unroll
        for (int r = 0; r < 4; ++r) dv[r] = dinv[rbase + r];
#pragma unroll
        for (int ct = 0; ct < 4; ++ct) {
            int col = ct * 16 + (lane & 15);
#pragma unroll
            for (int r = 0; r < 4; ++r)
                h1b[(size_t)(rbase + r) * 64 + col] = f2bf(acc[rt][ct][r] * dv[r]);
        }
    }
}

// ============ layer2: h2b = dinv * (relu(dinv*agg + b1) @ W2)  (R8 form) ====

__global__ __launch_bounds__(256) void layer2_k(const int* __restrict__ offsets,
        const int* __restrict__ ends, const int* __restrict__ srt_src,
        const float* __restrict__ dinv, const u16* __restrict__ h1b,
        const float* __restrict__ b1, const float* __restrict__ W2,
        u16* __restrict__ h2b) {
    __shared__ float W2s[64 * 32];
    __shared__ float b1s[64];
    for (int i = threadIdx.x; i < 64 * 32; i += 256) W2s[i] = W2[i];
    if (threadIdx.x < 64) b1s[threadIdx.x] = b1[threadIdx.x];
    __syncthreads();
    int lane = threadIdx.x & 63;
    int f = lane & 15, q = lane >> 4;
    int v0 = blockIdx.x * 8 + (threadIdx.x >> 6) * 2;   // grid = N/8
    int v1 = v0 + 1;
    int i0 = offsets[v0], e0 = ends[v0];
    int i1 = offsets[v1], e1 = ends[v1];
    const uint2* rows = (const uint2*)h1b;              // row s = rows + s*16
    float a0 = 0.f, a1 = 0.f, a2 = 0.f, a3 = 0.f;       // node0
    float c0 = 0.f, c1 = 0.f, c2 = 0.f, c3 = 0.f;       // node1
    while (i0 + 8 <= e0 && i1 + 8 <= e1) {
        int sA = srt_src[i0 + q];
        int sB = srt_src[i0 + 4 + q];
        int sC = srt_src[i1 + q];
        int sD = srt_src[i1 + 4 + q];
        uint2 pA = rows[sA * 16 + f];
        uint2 pB = rows[sB * 16 + f];
        uint2 pC = rows[sC * 16 + f];
        uint2 pD = rows[sD * 16 + f];
        acc2(pA.x, a0, a1); acc2(pA.y, a2, a3);
        acc2(pB.x, a0, a1); acc2(pB.y, a2, a3);
        acc2(pC.x, c0, c1); acc2(pC.y, c2, c3);
        acc2(pD.x, c0, c1); acc2(pD.y, c2, c3);
        i0 += 8; i1 += 8;
    }
    for (; i0 + 8 <= e0; i0 += 8) {
        int sA = srt_src[i0 + q], sB = srt_src[i0 + 4 + q];
        uint2 pA = rows[sA * 16 + f], pB = rows[sB * 16 + f];
        acc2(pA.x, a0, a1); acc2(pA.y, a2, a3);
        acc2(pB.x, a0, a1); acc2(pB.y, a2, a3);
    }
    for (; i0 < e0; i0 += 4) {
        int j = i0 + q;
        if (j < e0) {
            int s = srt_src[j];
            uint2 p = rows[s * 16 + f];
            acc2(p.x, a0, a1); acc2(p.y, a2, a3);
        }
    }
    for (; i1 + 8 <= e1; i1 += 8) {
        int sA = srt_src[i1 + q], sB = srt_src[i1 + 4 + q];
        uint2 pA = rows[sA * 16 + f], pB = rows[sB * 16 + f];
        acc2(pA.x, c0, c1); acc2(pA.y, c2, c3);
        acc2(pB.x, c0, c1); acc2(pB.y, c2, c3);
    }
    for (; i1 < e1; i1 += 4) {
        int j = i1 + q;
        if (j < e1) {
            int s = srt_src[j];
            uint2 p = rows[s * 16 + f];
            acc2(p.x, c0, c1); acc2(p.y, c2, c3);
        }
    }
    a0 += __shfl_xor(a0, 16, 64); a0 += __shfl_xor(a0, 32, 64);
    a1 += __shfl_xor(a1, 16, 64); a1 += __shfl_xor(a1, 32, 64);
    a2 += __shfl_xor(a2, 16, 64); a2 += __shfl_xor(a2, 32, 64);
    a3 += __shfl_xor(a3, 16, 64); a3 += __shfl_xor(a3, 32, 64);
    c0 += __shfl_xor(c0, 16, 64); c0 += __shfl_xor(c0, 32, 64);
    c1 += __shfl_xor(c1, 16, 64); c1 += __shfl_xor(c1, 32, 64);
    c2 += __shfl_xor(c2, 16, 64); c2 += __shfl_xor(c2, 32, 64);
    c3 += __shfl_xor(c3, 16, 64); c3 += __shfl_xor(c3, 32, 64);
    bool lo = (lane < 32);
    float dv = lo ? dinv[v0] : dinv[v1];
    float t0 = lo ? a0 : c0;
    float t1 = lo ? a1 : c1;
    float t2 = lo ? a2 : c2;
    float t3 = lo ? a3 : c3;
    float r0 = fmaxf(fmaf(dv, t0, b1s[4 * f + 0]), 0.f);
    float r1 = fmaxf(fmaf(dv, t1, b1s[4 * f + 1]), 0.f);
    float r2 = fmaxf(fmaf(dv, t2, b1s[4 * f + 2]), 0.f);
    float r3 = fmaxf(fmaf(dv, t3, b1s[4 * f + 3]), 0.f);
    int c = lane & 31;
    float o = 0.f;
#pragma unroll
    for (int j2 = 0; j2 < 16; ++j2) {
        float R0 = __shfl(r0, j2, 16);
        float R1 = __shfl(r1, j2, 16);
        float R2 = __shfl(r2, j2, 16);
        float R3 = __shfl(r3, j2, 16);
        o = fmaf(R0, W2s[(4 * j2 + 0) * 32 + c], o);
        o = fmaf(R1, W2s[(4 * j2 + 1) * 32 + c], o);
        o = fmaf(R2, W2s[(4 * j2 + 2) * 32 + c], o);
        o = fmaf(R3, W2s[(4 * j2 + 3) * 32 + c], o);
    }
    int vst = lo ? v0 : v1;
    h2b[vst * 32 + c] = f2bf(dv * o);
}

// ============ layer3: out = relu(dinv*agg(h2b) + b2) @ Wfc + bfc  (R8 form) ==

#define GATH3(ii, A, B, C, D) { \
    int s_ = srt_src[(ii) + oc]; \
    uint2 p_ = rows[s_ * 8 + f]; \
    acc2(p_.x, A, B); acc2(p_.y, C, D); }

__global__ __launch_bounds__(256) void layer3_k(const int* __restrict__ offsets,
        const int* __restrict__ ends, const int* __restrict__ srt_src,
        const float* __restrict__ dinv, const u16* __restrict__ h2b,
        const float* __restrict__ b2, const float* __restrict__ Wfc,
        const float* __restrict__ bfc, float* __restrict__ out) {
    int lane = threadIdx.x & 63;
    int f = lane & 7, oc = lane >> 3;
    int vb = blockIdx.x * 16 + (threadIdx.x >> 6) * 4;   // grid = N/16
    int i0 = offsets[vb],     e0 = ends[vb];
    int i1 = offsets[vb + 1], e1 = ends[vb + 1];
    int i2 = offsets[vb + 2], e2 = ends[vb + 2];
    int i3 = offsets[vb + 3], e3 = ends[vb + 3];
    const uint2* rows = (const uint2*)h2b;               // row s = rows + s*8
    float A0=0.f,A1=0.f,A2=0.f,A3=0.f, B0=0.f,B1=0.f,B2=0.f,B3=0.f;
    float C0=0.f,C1=0.f,C2=0.f,C3=0.f, D0=0.f,D1=0.f,D2=0.f,D3=0.f;
    while (i0 + 8 <= e0 && i1 + 8 <= e1 && i2 + 8 <= e2 && i3 + 8 <= e3) {
        GATH3(i0, A0, A1, A2, A3);
        GATH3(i1, B0, B1, B2, B3);
        GATH3(i2, C0, C1, C2, C3);
        GATH3(i3, D0, D1, D2, D3);
        i0 += 8; i1 += 8; i2 += 8; i3 += 8;
    }
    while (i0 + 8 <= e0) { GATH3(i0, A0, A1, A2, A3); i0 += 8; }
    if (i0 + oc < e0)    { GATH3(i0, A0, A1, A2, A3); }
    while (i1 + 8 <= e1) { GATH3(i1, B0, B1, B2, B3); i1 += 8; }
    if (i1 + oc < e1)    { GATH3(i1, B0, B1, B2, B3); }
    while (i2 + 8 <= e2) { GATH3(i2, C0, C1, C2, C3); i2 += 8; }
    if (i2 + oc < e2)    { GATH3(i2, C0, C1, C2, C3); }
    while (i3 + 8 <= e3) { GATH3(i3, D0, D1, D2, D3); i3 += 8; }
    if (i3 + oc < e3)    { GATH3(i3, D0, D1, D2, D3); }
#define RED3(X) X += __shfl_xor(X, 8, 64); X += __shfl_xor(X, 16, 64); X += __shfl_xor(X, 32, 64)
    RED3(A0); RED3(A1); RED3(A2); RED3(A3);
    RED3(B0); RED3(B1); RED3(B2); RED3(B3);
    RED3(C0); RED3(C1); RED3(C2); RED3(C3);
    RED3(D0); RED3(D1); RED3(D2); RED3(D3);
    float w0 = Wfc[4 * f + 0], w1 = Wfc[4 * f + 1];
    float w2 = Wfc[4 * f + 2], w3 = Wfc[4 * f + 3];
    float g0 = b2[4 * f + 0], g1 = b2[4 * f + 1];
    float g2 = b2[4 * f + 2], g3 = b2[4 * f + 3];
    float dv0 = dinv[vb], dv1 = dinv[vb + 1], dv2 = dinv[vb + 2], dv3 = dinv[vb + 3];
    float p0 = fmaxf(fmaf(dv0, A0, g0), 0.f) * w0 + fmaxf(fmaf(dv0, A1, g1), 0.f) * w1
             + fmaxf(fmaf(dv0, A2, g2), 0.f) * w2 + fmaxf(fmaf(dv0, A3, g3), 0.f) * w3;
    float p1 = fmaxf(fmaf(dv1, B0, g0), 0.f) * w0 + fmaxf(fmaf(dv1, B1, g1), 0.f) * w1
             + fmaxf(fmaf(dv1, B2, g2), 0.f) * w2 + fmaxf(fmaf(dv1, B3, g3), 0.f) * w3;
    float p2 = fmaxf(fmaf(dv2, C0, g0), 0.f) * w0 + fmaxf(fmaf(dv2, C1, g1), 0.f) * w1
             + fmaxf(fmaf(dv2, C2, g2), 0.f) * w2 + fmaxf(fmaf(dv2, C3, g3), 0.f) * w3;
    float p3 = fmaxf(fmaf(dv3, D0, g0), 0.f) * w0 + fmaxf(fmaf(dv3, D1, g1), 0.f) * w1
             + fmaxf(fmaf(dv3, D2, g2), 0.f) * w2 + fmaxf(fmaf(dv3, D3, g3), 0.f) * w3;
#define REDP(X) X += __shfl_xor(X, 1, 64); X += __shfl_xor(X, 2, 64); X += __shfl_xor(X, 4, 64)
    REDP(p0); REDP(p1); REDP(p2); REDP(p3);
    if (lane == 0) {
        float bb = bfc[0];
        out[vb + 0] = p0 + bb;
        out[vb + 1] = p1 + bb;
        out[vb + 2] = p2 + bb;
        out[vb + 3] = p3 + bb;
    }
}

// ============ launch ============

extern "C" void kernel_launch(void* const* d_in, const int* in_sizes, int n_in,
                              void* d_out, int out_size, void* d_ws, size_t ws_size,
                              hipStream_t stream) {
    const float* x   = (const float*)d_in[0];
    const int*   ei  = (const int*)d_in[1];
    const float* W1  = (const float*)d_in[2];
    const float* b1  = (const float*)d_in[3];
    const float* W2  = (const float*)d_in[4];
    const float* b2  = (const float*)d_in[5];
    const float* Wfc = (const float*)d_in[6];
    const float* bfc = (const float*)d_in[7];
    float* out = (float*)d_out;

    const int E = in_sizes[1] / 2;
    const int TOT = E + N_NODES;
    const int* src = ei;
    const int* dst = ei + E;

    // workspace layout (ints)
    int*   bcur    = (int*)d_ws;                       // 256
    int*   offsets = bcur + 256;                       // N
    int*   ends    = offsets + N_NODES;                // N
    int*   srt_src = ends + N_NODES;                   // NBKT*SLACK (~2.0M)
    u32*   bktBuf  = (u32*)(srt_src + NBKT * SLACK);   // NBKT*SLACK
    float* dinv    = (float*)(bktBuf + NBKT * SLACK);  // N
    u16*   h1b     = (u16*)(dinv + N_NODES);           // 64N bf16
    u16*   h2b     = h1b + (size_t)N_NODES * 64;       // 32N bf16

    const int NCH = (TOT + CH - 1) / CH;

    initcur_k<<<1, 256, 0, stream>>>(bcur);
    partition_k<<<NCH, 256, 0, stream>>>(src, dst, bcur, bktBuf, E, TOT);
    buildfill_k<<<NBKT, 256, 0, stream>>>(bcur, bktBuf, offsets, ends, dinv,
                                          srt_src);

    const int GB1 = (N_NODES / 32 + 3) / 4;   // 782 blocks x 4 waves x 32 rows
    gemm1_k<<<GB1, 256, 0, stream>>>(x, W1, dinv, h1b);

    layer2_k<<<N_NODES / 8, 256, 0, stream>>>(offsets, ends, srt_src, dinv, h1b,
                                              b1, W2, h2b);
    layer3_k<<<N_NODES / 16, 256, 0, stream>>>(offsets, ends, srt_src, dinv, h2b,
                                               b2, Wfc, bfc, out);
}